// Round 2
// baseline (1784.972 us; speedup 1.0000x reference)
//
#include <hip/hip_runtime.h>
#include <math.h>

#define BATCH 32
#define TSEQ  4096
#define HD    128
#define NST   128
#define BT    (BATCH*TSEQ)     // 131072
#define LC    64               // scan chunk length
#define NCHK  (TSEQ/LC)        // 64 chunks

typedef unsigned short bf16;

__device__ inline float bf2f(bf16 s) {
    union { unsigned int u; float f; } v; v.u = ((unsigned int)s) << 16; return v.f;
}
__device__ inline bf16 f2bf(float f) {
    union { float f; unsigned int u; } v; v.f = f;
    unsigned int u = v.u;
    unsigned int r = (u + 0x7fffu + ((u >> 16) & 1u)) >> 16;
    return (bf16)r;
}
__device__ inline float2 cmul2(float2 a, float2 b) {
    return make_float2(a.x*b.x - a.y*b.y, a.x*b.y + a.y*b.x);
}
__device__ inline float gelu_f(float x) {
    return 0.5f * x * (1.f + erff(x * 0.70710678118654752f));
}

// ---------------- S5 parameter prep ----------------
__global__ void prep_s5(const float* __restrict__ Lam_re, const float* __restrict__ Lam_im,
                        const float* __restrict__ B_re,  const float* __restrict__ B_im,
                        const float* __restrict__ C_re,  const float* __restrict__ C_im,
                        const float* __restrict__ log_step,
                        float* __restrict__ Wbu, float* __restrict__ Wc,
                        float4* __restrict__ coefs)
{
    int i = blockIdx.x;          // layer
    int n = threadIdx.x;         // state
    int in = i*NST + n;
    float lr = Lam_re[in], li = Lam_im[in];
    float dt = expf(log_step[in]);
    float ldr = lr*dt, ldi = li*dt;
    float ea = expf(ldr);
    float ar = ea*cosf(ldi), ai = ea*sinf(ldi);
    float xx = ar - 1.f, yy = ai;
    float den = lr*lr + li*li;
    float sr = (xx*lr + yy*li)/den;
    float si = (yy*lr - xx*li)/den;
    float2 p = make_float2(ar, ai);
    #pragma unroll
    for (int q = 0; q < 6; ++q) p = cmul2(p, p);   // a^64
    coefs[in] = make_float4(ar, ai, p.x, p.y);

    const float* br = B_re + (size_t)in*HD;
    const float* bi = B_im + (size_t)in*HD;
    float* wb = Wbu + (size_t)i*HD*2*NST;
    for (int h = 0; h < HD; ++h) {
        float brv = br[h], biv = bi[h];
        wb[h*2*NST + 2*n]     = sr*brv - si*biv;
        wb[h*2*NST + 2*n + 1] = sr*biv + si*brv;
    }
    const float* cr = C_re + (size_t)i*HD*NST;
    const float* ci = C_im + (size_t)i*HD*NST;
    float* wc = Wc + (size_t)i*2*NST*HD;
    for (int h = 0; h < HD; ++h) {
        wc[(2*n)*HD + h]   =  2.f * cr[h*NST + n];
        wc[(2*n+1)*HD + h] = -2.f * ci[h*NST + n];
    }
}

// transpose conv weights [c][ic][k] -> [k][ic][c]
__global__ void prep_wT(const float* __restrict__ w1, const float* __restrict__ w2,
                        float* __restrict__ wT1, float* __restrict__ wT2)
{
    int idx = blockIdx.x*256 + threadIdx.x;
    if (idx >= 2*5*128*128) return;
    const float* w = (idx < 81920) ? w1 : w2;
    float* wt      = (idx < 81920) ? wT1 : wT2;
    int r = idx % 81920;
    int k  = r / 16384;
    int ic = (r / 128) % 128;
    int c  = r % 128;
    wt[r] = w[(c*128 + ic)*5 + k];
}

// ---------------- LayerNorm (H=128): one wave per row, bf16 out ----------------
__global__ __launch_bounds__(256) void ln_kernel(const float* __restrict__ X,
                                                 bf16* __restrict__ out,
                                                 const float* __restrict__ g,
                                                 const float* __restrict__ b)
{
    int lane = threadIdx.x & 63;
    size_t row = (size_t)blockIdx.x*4 + (threadIdx.x >> 6);
    const float* xr = X + row*HD;
    float2 v = *(const float2*)&xr[lane*2];
    float s = v.x + v.y;
    float s2 = v.x*v.x + v.y*v.y;
    #pragma unroll
    for (int off = 32; off >= 1; off >>= 1) {
        s  += __shfl_xor(s,  off);
        s2 += __shfl_xor(s2, off);
    }
    float mu  = s * (1.f/128.f);
    float var = s2 * (1.f/128.f) - mu*mu;
    float rs  = rsqrtf(var + 1e-5f);
    float2 gv = *(const float2*)&g[lane*2];
    float2 bv = *(const float2*)&b[lane*2];
    float ox = (v.x-mu)*rs*gv.x + bv.x;
    float oy = (v.y-mu)*rs*gv.y + bv.y;
    *(ushort2*)&out[row*HD + lane*2] = make_ushort2(f2bf(ox), f2bf(oy));
}

// ---------------- generic tiled GEMM, fused epilogues ----------------
// EPI: 0 = none; 1 = gelu(acc+bias); 2 = acc+bias+resid; 3 = resid+acc+u*dskip
template<int K, int NCOL, int EPI, typename TA>
__global__ __launch_bounds__(256) void gemm_kernel(
    const TA* __restrict__ A,      // [BT, K]
    const float* __restrict__ Bm,  // [K, NCOL]
    float* out,                    // [BT, NCOL]   (may alias resid)
    const float* __restrict__ bias,
    const float* resid,
    const bf16* __restrict__ u,
    const float* __restrict__ dskip)
{
    const int BK = 32;
    __shared__ float As[BK][64+4];
    __shared__ float Bs[BK][64+4];
    int tid  = threadIdx.x;
    int row0 = blockIdx.x * 64;
    int col0 = blockIdx.y * 64;
    int tm = (tid / 16) * 4;
    int tn = (tid % 16) * 4;
    float acc[4][4] = {};

    for (int k0 = 0; k0 < K; k0 += BK) {
        {
            int lr = tid / 8;
            int lk = (tid % 8) * 4;
            #pragma unroll
            for (int it = 0; it < 2; ++it) {
                int r = lr + it*32;
                float4 v;
                if constexpr (sizeof(TA) == 2) {
                    ushort4 q = *(const ushort4*)&A[(size_t)(row0 + r)*K + k0 + lk];
                    v = make_float4(bf2f(q.x), bf2f(q.y), bf2f(q.z), bf2f(q.w));
                } else {
                    v = *(const float4*)&A[(size_t)(row0 + r)*K + k0 + lk];
                }
                As[lk+0][r] = v.x; As[lk+1][r] = v.y; As[lk+2][r] = v.z; As[lk+3][r] = v.w;
            }
        }
        {
            int lk = tid / 16;
            int ln = (tid % 16) * 4;
            #pragma unroll
            for (int it = 0; it < 2; ++it) {
                int kk = lk + it*16;
                float4 v = *(const float4*)&Bm[(size_t)(k0 + kk)*NCOL + col0 + ln];
                *(float4*)&Bs[kk][ln] = v;
            }
        }
        __syncthreads();
        #pragma unroll
        for (int k = 0; k < BK; ++k) {
            float4 a4 = *(const float4*)&As[k][tm];
            float4 b4 = *(const float4*)&Bs[k][tn];
            acc[0][0] += a4.x*b4.x; acc[0][1] += a4.x*b4.y; acc[0][2] += a4.x*b4.z; acc[0][3] += a4.x*b4.w;
            acc[1][0] += a4.y*b4.x; acc[1][1] += a4.y*b4.y; acc[1][2] += a4.y*b4.z; acc[1][3] += a4.y*b4.w;
            acc[2][0] += a4.z*b4.x; acc[2][1] += a4.z*b4.y; acc[2][2] += a4.z*b4.z; acc[2][3] += a4.z*b4.w;
            acc[3][0] += a4.w*b4.x; acc[3][1] += a4.w*b4.y; acc[3][2] += a4.w*b4.z; acc[3][3] += a4.w*b4.w;
        }
        __syncthreads();
    }

    #pragma unroll
    for (int i = 0; i < 4; ++i) {
        size_t row  = (size_t)row0 + tm + i;
        size_t oidx = row*NCOL + col0 + tn;
        float4 v = make_float4(acc[i][0], acc[i][1], acc[i][2], acc[i][3]);
        if (EPI == 1) {
            float4 bv = *(const float4*)&bias[col0 + tn];
            v.x = gelu_f(v.x + bv.x); v.y = gelu_f(v.y + bv.y);
            v.z = gelu_f(v.z + bv.z); v.w = gelu_f(v.w + bv.w);
        } else if (EPI == 2) {
            float4 bv = *(const float4*)&bias[col0 + tn];
            float4 rv = *(const float4*)&resid[oidx];
            v.x += bv.x + rv.x; v.y += bv.y + rv.y; v.z += bv.z + rv.z; v.w += bv.w + rv.w;
        } else if (EPI == 3) {
            float4 rv = *(const float4*)&resid[oidx];
            ushort4 uq = *(const ushort4*)&u[oidx];
            float4 dv = *(const float4*)&dskip[col0 + tn];
            v.x = rv.x + v.x + bf2f(uq.x)*dv.x; v.y = rv.y + v.y + bf2f(uq.y)*dv.y;
            v.z = rv.z + v.z + bf2f(uq.z)*dv.z; v.w = rv.w + v.w + bf2f(uq.w)*dv.w;
        }
        *(float4*)&out[oidx] = v;
    }
}

// ---------------- chunked scan: x_t = a*x_{t-1} + Bu_t ----------------
__global__ __launch_bounds__(256) void scan_local(float2* __restrict__ xs,
                                                  const float4* __restrict__ coefs,
                                                  float2* __restrict__ carry)
{
    int flat = blockIdx.x*256 + threadIdx.x;  // 2^18
    int n = flat & 127;
    int b = (flat >> 7) & 31;
    int c = flat >> 12;                        // chunk
    float4 cf = coefs[n];
    float2 a = make_float2(cf.x, cf.y);
    float2* base = xs + ((size_t)(b*TSEQ + c*LC))*NST + n;
    float2 x = make_float2(0.f, 0.f);
    for (int j = 0; j < LC; ++j) {
        float2 v = base[(size_t)j*NST];
        x = make_float2(a.x*x.x - a.y*x.y + v.x, a.x*x.y + a.y*x.x + v.y);
        base[(size_t)j*NST] = x;
    }
    carry[c*(BATCH*NST) + b*NST + n] = x;
}

__global__ void scan_carry(float2* __restrict__ carry, const float4* __restrict__ coefs)
{
    int flat = blockIdx.x*256 + threadIdx.x;  // 4096 = B*N
    int n = flat & 127;
    float4 cf = coefs[n];
    float2 aL = make_float2(cf.z, cf.w);
    float2 x = make_float2(0.f, 0.f);
    for (int c = 0; c < NCHK; ++c) {
        float2* p = carry + c*(BATCH*NST) + flat;
        float2 v = *p;
        *p = x;                                // exclusive prefix
        x = make_float2(aL.x*x.x - aL.y*x.y + v.x, aL.x*x.y + aL.y*x.x + v.y);
    }
}

__global__ __launch_bounds__(256) void scan_fix(float2* __restrict__ xs,
                                                const float4* __restrict__ coefs,
                                                const float2* __restrict__ carry)
{
    int flat = blockIdx.x*256 + threadIdx.x;
    int n = flat & 127;
    int b = (flat >> 7) & 31;
    int c = flat >> 12;
    if (c == 0) return;
    float2 cin = carry[c*(BATCH*NST) + b*NST + n];
    float4 cf = coefs[n];
    float2 a = make_float2(cf.x, cf.y);
    float2* base = xs + ((size_t)(b*TSEQ + c*LC))*NST + n;
    float2 p = a;
    for (int j = 0; j < LC; ++j) {
        float2 add = cmul2(p, cin);
        float2 v = base[(size_t)j*NST];
        base[(size_t)j*NST] = make_float2(v.x + add.x, v.y + add.y);
        p = cmul2(p, a);
    }
}

// ---------------- conv1d stride2 k=5 pad2 + bias + relu ----------------
__global__ __launch_bounds__(128) void conv_kernel(const float* __restrict__ X,
                                                   const float* __restrict__ wT,
                                                   const float* __restrict__ bias,
                                                   float* __restrict__ out,
                                                   int Tin, int Lout)
{
    __shared__ float xt[128][36];
    int b  = blockIdx.x;
    int l0 = blockIdx.y * 16;
    int c  = threadIdx.x;
    int t0 = 2*l0 - 2;
    #pragma unroll
    for (int r = 0; r < 35; ++r) {
        int t = t0 + r;
        xt[c][r] = (t >= 0 && t < Tin) ? X[((size_t)b*Tin + t)*128 + c] : 0.f;
    }
    __syncthreads();
    float acc[16] = {};
    for (int ic = 0; ic < 128; ++ic) {
        float xf[36];
        #pragma unroll
        for (int q = 0; q < 9; ++q) {
            float4 v4 = *(const float4*)&xt[ic][q*4];
            xf[q*4+0]=v4.x; xf[q*4+1]=v4.y; xf[q*4+2]=v4.z; xf[q*4+3]=v4.w;
        }
        #pragma unroll
        for (int k = 0; k < 5; ++k) {
            float w = wT[(k*128 + ic)*128 + c];
            #pragma unroll
            for (int l = 0; l < 16; ++l)
                acc[l] += xf[2*l + k] * w;
        }
    }
    float bv = bias[c];
    #pragma unroll
    for (int l = 0; l < 16; ++l) {
        float v = acc[l] + bv;
        out[((size_t)b*Lout + l0 + l)*128 + c] = v > 0.f ? v : 0.f;
    }
}

// ---------------- adaptive avg pool: [32][1024][128] -> [32][128][64] ----------------
__global__ void pool_kernel(const float* __restrict__ Xc, float* __restrict__ out)
{
    int idx = blockIdx.x*256 + threadIdx.x;   // 262144
    int c = idx & 127;
    int d = (idx >> 7) & 63;
    int b = idx >> 13;
    float s = 0.f;
    #pragma unroll
    for (int j = 0; j < 16; ++j)
        s += Xc[((size_t)b*1024 + d*16 + j)*128 + c];
    out[((size_t)b*128 + c)*64 + d] = s * (1.f/16.f);
}

extern "C" void kernel_launch(void* const* d_in, const int* in_sizes, int n_in,
                              void* d_out, int out_size, void* d_ws, size_t ws_size,
                              hipStream_t stream)
{
    (void)in_sizes; (void)n_in; (void)out_size; (void)ws_size;
    const float* x_in    = (const float*)d_in[0];
    const float* ln1_g   = (const float*)d_in[1];
    const float* ln1_b   = (const float*)d_in[2];
    const float* ln2_g   = (const float*)d_in[3];
    const float* ln2_b   = (const float*)d_in[4];
    const float* Lam_re  = (const float*)d_in[5];
    const float* Lam_im  = (const float*)d_in[6];
    const float* B_re    = (const float*)d_in[7];
    const float* B_im    = (const float*)d_in[8];
    const float* C_re    = (const float*)d_in[9];
    const float* C_im    = (const float*)d_in[10];
    const float* D_skip  = (const float*)d_in[11];
    const float* log_step= (const float*)d_in[12];
    const float* W1      = (const float*)d_in[13];
    const float* b1      = (const float*)d_in[14];
    const float* W2      = (const float*)d_in[15];
    const float* b2      = (const float*)d_in[16];
    const float* conv1_w = (const float*)d_in[17];
    const float* conv1_b = (const float*)d_in[18];
    const float* conv2_w = (const float*)d_in[19];
    const float* conv2_b = (const float*)d_in[20];
    float* out = (float*)d_out;

    // Workspace layout (total ~227.1 MB; fits 256 MB):
    //   X   fp32 [BT,128]  @ 0          (64 MB)
    //   C   fp32 [BT,256]  @ 64 MB      (128 MB)  Bu/xs, h, conv1 out
    //   Abf bf16 [BT,128]  @ 192 MB     (32 MB)   xn
    //   params + carry     @ 224 MB     (~3.2 MB)
    char* ws = (char*)d_ws;
    float* X   = (float*)(ws);
    float* C   = (float*)(ws + (size_t)67108864);
    bf16*  Abf = (bf16*) (ws + (size_t)201326592);
    char*  wreg = ws + (size_t)234881024;
    float*  Wbu  = (float*)(wreg);                  // 262144 B
    float*  Wc   = (float*)(wreg + 262144);         // 262144 B
    float4* coefs= (float4*)(wreg + 524288);        // 4096 B
    float*  wT1  = (float*)(wreg + 528384);         // 327680 B
    float*  wT2  = (float*)(wreg + 856064);         // 327680 B
    float2* carry= (float2*)(wreg + 1183744);       // 2 MB

    prep_s5<<<2, 128, 0, stream>>>(Lam_re, Lam_im, B_re, B_im, C_re, C_im, log_step,
                                   Wbu, Wc, coefs);
    prep_wT<<<640, 256, 0, stream>>>(conv1_w, conv2_w, wT1, wT2);

    for (int i = 0; i < 2; ++i) {
        const float* src = (i == 0) ? x_in : X;     // layer input / residual
        // ---- S5 sub-block ----
        ln_kernel<<<BT/4, 256, 0, stream>>>(src, Abf, ln1_g + i*HD, ln1_b + i*HD);
        gemm_kernel<128,256,0,bf16><<<dim3(BT/64, 4), 256, 0, stream>>>(
            Abf, Wbu + (size_t)i*HD*2*NST, C, nullptr, nullptr, nullptr, nullptr);
        scan_local<<<1024, 256, 0, stream>>>((float2*)C, coefs + i*NST, carry);
        scan_carry<<<16, 256, 0, stream>>>(carry, coefs + i*NST);
        scan_fix<<<1024, 256, 0, stream>>>((float2*)C, coefs + i*NST, carry);
        gemm_kernel<256,128,3,float><<<dim3(BT/64, 2), 256, 0, stream>>>(
            C, Wc + (size_t)i*2*NST*HD, X, nullptr, src, Abf, D_skip + i*HD);
        // ---- MLP sub-block ----
        ln_kernel<<<BT/4, 256, 0, stream>>>(X, Abf, ln2_g + i*HD, ln2_b + i*HD);
        gemm_kernel<128,256,1,bf16><<<dim3(BT/64, 4), 256, 0, stream>>>(
            Abf, W1 + (size_t)i*HD*2*HD, C, b1 + i*2*HD, nullptr, nullptr, nullptr);
        gemm_kernel<256,128,2,float><<<dim3(BT/64, 2), 256, 0, stream>>>(
            C, W2 + (size_t)i*2*HD*HD, X, b2 + i*HD, X, nullptr, nullptr);
    }

    // ---- head: conv1 (X->C) -> conv2 (C->X) -> pool (X->out) ----
    conv_kernel<<<dim3(32, 128), 128, 0, stream>>>(X, wT1, conv1_b, C, 4096, 2048);
    conv_kernel<<<dim3(32, 64),  128, 0, stream>>>(C, wT2, conv2_b, X, 2048, 1024);
    pool_kernel<<<1024, 256, 0, stream>>>(X, out);
}

// Round 3
// 1195.895 us; speedup vs baseline: 1.4926x; 1.4926x over previous
//
#include <hip/hip_runtime.h>
#include <math.h>

#define BATCH 32
#define TSEQ  4096
#define HD    128
#define NST   128
#define BT    (BATCH*TSEQ)     // 131072
#define LC    64               // scan chunk length
#define NCHK  (TSEQ/LC)        // 64 chunks

typedef unsigned short bf16;
typedef __attribute__((ext_vector_type(8))) short bf16x8;   // 8 bf16 = 4 VGPRs (MFMA A/B frag)
typedef __attribute__((ext_vector_type(4))) float f32x4;    // MFMA C/D frag

__device__ inline float bf2f(bf16 s) {
    union { unsigned int u; float f; } v; v.u = ((unsigned int)s) << 16; return v.f;
}
__device__ inline bf16 f2bf(float f) {
    union { float f; unsigned int u; } v; v.f = f;
    unsigned int u = v.u;
    unsigned int r = (u + 0x7fffu + ((u >> 16) & 1u)) >> 16;
    return (bf16)r;
}
__device__ inline float2 cmul2(float2 a, float2 b) {
    return make_float2(a.x*b.x - a.y*b.y, a.x*b.y + a.y*b.x);
}
__device__ inline float gelu_f(float x) {
    return 0.5f * x * (1.f + erff(x * 0.70710678118654752f));
}

// ---------------- S5 parameter prep (bf16, transposed [N][K] for MFMA B) ----------------
__global__ void prep_s5(const float* __restrict__ Lam_re, const float* __restrict__ Lam_im,
                        const float* __restrict__ B_re,  const float* __restrict__ B_im,
                        const float* __restrict__ C_re,  const float* __restrict__ C_im,
                        const float* __restrict__ log_step,
                        bf16* __restrict__ Wbu_t,   // [2][256][128]  row 2n=Re, 2n+1=Im
                        bf16* __restrict__ Wc_t,    // [2][128][256]  col 2n=2Cre, 2n+1=-2Cim
                        float4* __restrict__ coefs)
{
    int i = blockIdx.x;          // layer
    int n = threadIdx.x;         // state
    int in = i*NST + n;
    float lr = Lam_re[in], li = Lam_im[in];
    float dt = expf(log_step[in]);
    float ldr = lr*dt, ldi = li*dt;
    float ea = expf(ldr);
    float ar = ea*cosf(ldi), ai = ea*sinf(ldi);
    float xx = ar - 1.f, yy = ai;
    float den = lr*lr + li*li;
    float sr = (xx*lr + yy*li)/den;
    float si = (yy*lr - xx*li)/den;
    float2 p = make_float2(ar, ai);
    #pragma unroll
    for (int q = 0; q < 6; ++q) p = cmul2(p, p);   // a^64
    coefs[in] = make_float4(ar, ai, p.x, p.y);

    const float* br = B_re + (size_t)in*HD;
    const float* bi = B_im + (size_t)in*HD;
    bf16* wb = Wbu_t + (size_t)i*256*128;
    for (int h = 0; h < HD; ++h) {
        float brv = br[h], biv = bi[h];
        wb[(2*n)*128 + h]   = f2bf(sr*brv - si*biv);
        wb[(2*n+1)*128 + h] = f2bf(sr*biv + si*brv);
    }
    const float* cr = C_re + (size_t)i*HD*NST;
    const float* ci = C_im + (size_t)i*HD*NST;
    bf16* wc = Wc_t + (size_t)i*128*256;
    for (int h = 0; h < HD; ++h) {
        wc[h*256 + 2*n]   = f2bf( 2.f * cr[h*NST + n]);
        wc[h*256 + 2*n+1] = f2bf(-2.f * ci[h*NST + n]);
    }
}

// MLP weights -> bf16 transposed [N][K]
__global__ void prep_w12(const float* __restrict__ W1, const float* __restrict__ W2,
                         bf16* __restrict__ W1t, bf16* __restrict__ W2t)
{
    int idx = blockIdx.x*256 + threadIdx.x;
    if (idx < 65536) {                       // W1t[i][f][h] = W1[i][h][f]
        int i = idx >> 15, r = idx & 32767;
        int f = r >> 7, h = r & 127;
        W1t[idx] = f2bf(W1[(size_t)i*32768 + h*256 + f]);
    } else if (idx < 131072) {               // W2t[i][h][f] = W2[i][f][h]
        int t = idx - 65536;
        int i = t >> 15, r = t & 32767;
        int h = r >> 8, f = r & 255;
        W2t[t] = f2bf(W2[(size_t)i*32768 + f*128 + h]);
    }
}

// transpose conv weights [c][ic][k] -> [k][ic][c] (fp32, unchanged)
__global__ void prep_wT(const float* __restrict__ w1, const float* __restrict__ w2,
                        float* __restrict__ wT1, float* __restrict__ wT2)
{
    int idx = blockIdx.x*256 + threadIdx.x;
    if (idx >= 2*5*128*128) return;
    const float* w = (idx < 81920) ? w1 : w2;
    float* wt      = (idx < 81920) ? wT1 : wT2;
    int r = idx % 81920;
    int k  = r / 16384;
    int ic = (r / 128) % 128;
    int c  = r % 128;
    wt[r] = w[(c*128 + ic)*5 + k];
}

// ---------------- LayerNorm (H=128): one wave per row, bf16 out ----------------
__global__ __launch_bounds__(256) void ln_kernel(const float* __restrict__ X,
                                                 bf16* __restrict__ out,
                                                 const float* __restrict__ g,
                                                 const float* __restrict__ b)
{
    int lane = threadIdx.x & 63;
    size_t row = (size_t)blockIdx.x*4 + (threadIdx.x >> 6);
    const float* xr = X + row*HD;
    float2 v = *(const float2*)&xr[lane*2];
    float s = v.x + v.y;
    float s2 = v.x*v.x + v.y*v.y;
    #pragma unroll
    for (int off = 32; off >= 1; off >>= 1) {
        s  += __shfl_xor(s,  off);
        s2 += __shfl_xor(s2, off);
    }
    float mu  = s * (1.f/128.f);
    float var = s2 * (1.f/128.f) - mu*mu;
    float rs  = rsqrtf(var + 1e-5f);
    float2 gv = *(const float2*)&g[lane*2];
    float2 bv = *(const float2*)&b[lane*2];
    float ox = (v.x-mu)*rs*gv.x + bv.x;
    float oy = (v.y-mu)*rs*gv.y + bv.y;
    *(ushort2*)&out[row*HD + lane*2] = make_ushort2(f2bf(ox), f2bf(oy));
}

// ---------------- bf16 MFMA GEMM, 128x128 tile, BK=64, fused epilogues ----------------
// A: [BT,K] (bf16, or fp32 converted during staging). Bt: [NCOL][K] bf16 (pre-transposed).
// out fp32 [BT,NCOL]. EPI: 0 none; 1 gelu(acc+bias); 2 acc+bias+resid; 3 resid+acc+u*dskip
template<int K, int NCOL, int EPI, typename TA>
__global__ __launch_bounds__(256) void gemm_mfma(
    const TA*  __restrict__ A,
    const bf16* __restrict__ Bt,
    float* out,                      // may alias resid (same-elem read-then-write only)
    const float* __restrict__ bias,
    const float* resid,
    const bf16* __restrict__ u,
    const float* __restrict__ dskip)
{
    __shared__ bf16 As[128][72];     // +8 pad: row stride 144B kills frag-read conflicts
    __shared__ bf16 Bs[128][72];
    int tid  = threadIdx.x;
    int lane = tid & 63;
    int wave = tid >> 6;
    int wm = wave >> 1, wn = wave & 1;          // 2x2 waves, 64x64 each
    int quad = lane >> 4, cl = lane & 15;
    int row0 = blockIdx.x * 128;
    int col0 = blockIdx.y * 128;

    f32x4 acc[4][4] = {};

    for (int k0 = 0; k0 < K; k0 += 64) {
        // ---- stage A tile (128 rows x 64 k) ----
        if constexpr (sizeof(TA) == 2) {
            #pragma unroll
            for (int it = 0; it < 4; ++it) {
                int idx = it*256 + tid;              // 0..1023
                int r = idx >> 3, kof = (idx & 7) * 8;
                bf16x8 v = *(const bf16x8*)(A + (size_t)(row0 + r)*K + k0 + kof);
                *(bf16x8*)&As[r][kof] = v;
            }
        } else {
            #pragma unroll
            for (int it = 0; it < 8; ++it) {
                int idx = it*256 + tid;              // 0..2047
                int r = idx >> 4, kof = (idx & 15) * 4;
                float4 f = *(const float4*)(A + (size_t)(row0 + r)*K + k0 + kof);
                ushort4 h;
                h.x = f2bf(f.x); h.y = f2bf(f.y); h.z = f2bf(f.z); h.w = f2bf(f.w);
                *(ushort4*)&As[r][kof] = h;
            }
        }
        // ---- stage B tile (128 cols x 64 k) ----
        #pragma unroll
        for (int it = 0; it < 4; ++it) {
            int idx = it*256 + tid;
            int n = idx >> 3, kof = (idx & 7) * 8;
            bf16x8 v = *(const bf16x8*)(Bt + (size_t)(col0 + n)*K + k0 + kof);
            *(bf16x8*)&Bs[n][kof] = v;
        }
        __syncthreads();
        #pragma unroll
        for (int kk = 0; kk < 64; kk += 32) {
            bf16x8 af[4], bfr[4];
            #pragma unroll
            for (int i = 0; i < 4; ++i)
                af[i] = *(const bf16x8*)&As[wm*64 + i*16 + cl][kk + quad*8];
            #pragma unroll
            for (int j = 0; j < 4; ++j)
                bfr[j] = *(const bf16x8*)&Bs[wn*64 + j*16 + cl][kk + quad*8];
            #pragma unroll
            for (int i = 0; i < 4; ++i)
                #pragma unroll
                for (int j = 0; j < 4; ++j)
                    acc[i][j] = __builtin_amdgcn_mfma_f32_16x16x32_bf16(
                                    af[i], bfr[j], acc[i][j], 0, 0, 0);
        }
        __syncthreads();
    }

    // ---- epilogue: C/D layout col=lane&15, row=quad*4+reg ----
    #pragma unroll
    for (int j = 0; j < 4; ++j) {
        int gcol = col0 + wn*64 + j*16 + cl;
        float bias_v = (EPI == 1 || EPI == 2) ? bias[gcol] : 0.f;
        float dv     = (EPI == 3) ? dskip[gcol] : 0.f;
        #pragma unroll
        for (int i = 0; i < 4; ++i) {
            #pragma unroll
            for (int r = 0; r < 4; ++r) {
                int grow = row0 + wm*64 + i*16 + quad*4 + r;
                size_t oidx = (size_t)grow*NCOL + gcol;
                float v = acc[i][j][r];
                if (EPI == 1)      v = gelu_f(v + bias_v);
                else if (EPI == 2) v = v + bias_v + resid[oidx];
                else if (EPI == 3) v = resid[oidx] + v + bf2f(u[oidx])*dv;
                out[oidx] = v;
            }
        }
    }
}

// ---------------- chunked scan: x_t = a*x_{t-1} + Bu_t (fp32) ----------------
__global__ __launch_bounds__(256) void scan_local(float2* __restrict__ xs,
                                                  const float4* __restrict__ coefs,
                                                  float2* __restrict__ carry)
{
    int flat = blockIdx.x*256 + threadIdx.x;  // 2^18
    int n = flat & 127;
    int b = (flat >> 7) & 31;
    int c = flat >> 12;
    float4 cf = coefs[n];
    float2 a = make_float2(cf.x, cf.y);
    float2* base = xs + ((size_t)(b*TSEQ + c*LC))*NST + n;
    float2 x = make_float2(0.f, 0.f);
    for (int j = 0; j < LC; ++j) {
        float2 v = base[(size_t)j*NST];
        x = make_float2(a.x*x.x - a.y*x.y + v.x, a.x*x.y + a.y*x.x + v.y);
        base[(size_t)j*NST] = x;
    }
    carry[c*(BATCH*NST) + b*NST + n] = x;
}

__global__ void scan_carry(float2* __restrict__ carry, const float4* __restrict__ coefs)
{
    int flat = blockIdx.x*256 + threadIdx.x;  // 4096 = B*N
    int n = flat & 127;
    float4 cf = coefs[n];
    float2 aL = make_float2(cf.z, cf.w);
    float2 x = make_float2(0.f, 0.f);
    for (int c = 0; c < NCHK; ++c) {
        float2* p = carry + c*(BATCH*NST) + flat;
        float2 v = *p;
        *p = x;                                // exclusive prefix
        x = make_float2(aL.x*x.x - aL.y*x.y + v.x, aL.x*x.y + aL.y*x.x + v.y);
    }
}

__global__ __launch_bounds__(256) void scan_fix(float2* __restrict__ xs,
                                                const float4* __restrict__ coefs,
                                                const float2* __restrict__ carry)
{
    int flat = blockIdx.x*256 + threadIdx.x;
    int n = flat & 127;
    int b = (flat >> 7) & 31;
    int c = flat >> 12;
    if (c == 0) return;
    float2 cin = carry[c*(BATCH*NST) + b*NST + n];
    float4 cf = coefs[n];
    float2 a = make_float2(cf.x, cf.y);
    float2* base = xs + ((size_t)(b*TSEQ + c*LC))*NST + n;
    float2 p = a;
    for (int j = 0; j < LC; ++j) {
        float2 add = cmul2(p, cin);
        float2 v = base[(size_t)j*NST];
        base[(size_t)j*NST] = make_float2(v.x + add.x, v.y + add.y);
        p = cmul2(p, a);
    }
}

// ---------------- conv1d stride2 k=5 pad2 + bias + relu ----------------
__global__ __launch_bounds__(128) void conv_kernel(const float* __restrict__ X,
                                                   const float* __restrict__ wT,
                                                   const float* __restrict__ bias,
                                                   float* __restrict__ out,
                                                   int Tin, int Lout)
{
    __shared__ float xt[128][36];
    int b  = blockIdx.x;
    int l0 = blockIdx.y * 16;
    int c  = threadIdx.x;
    int t0 = 2*l0 - 2;
    #pragma unroll
    for (int r = 0; r < 35; ++r) {
        int t = t0 + r;
        xt[c][r] = (t >= 0 && t < Tin) ? X[((size_t)b*Tin + t)*128 + c] : 0.f;
    }
    __syncthreads();
    float acc[16] = {};
    for (int ic = 0; ic < 128; ++ic) {
        float xf[36];
        #pragma unroll
        for (int q = 0; q < 9; ++q) {
            float4 v4 = *(const float4*)&xt[ic][q*4];
            xf[q*4+0]=v4.x; xf[q*4+1]=v4.y; xf[q*4+2]=v4.z; xf[q*4+3]=v4.w;
        }
        #pragma unroll
        for (int k = 0; k < 5; ++k) {
            float w = wT[(k*128 + ic)*128 + c];
            #pragma unroll
            for (int l = 0; l < 16; ++l)
                acc[l] += xf[2*l + k] * w;
        }
    }
    float bv = bias[c];
    #pragma unroll
    for (int l = 0; l < 16; ++l) {
        float v = acc[l] + bv;
        out[((size_t)b*Lout + l0 + l)*128 + c] = v > 0.f ? v : 0.f;
    }
}

// ---------------- adaptive avg pool: [32][1024][128] -> [32][128][64] ----------------
__global__ void pool_kernel(const float* __restrict__ Xc, float* __restrict__ out)
{
    int idx = blockIdx.x*256 + threadIdx.x;   // 262144
    int c = idx & 127;
    int d = (idx >> 7) & 63;
    int b = idx >> 13;
    float s = 0.f;
    #pragma unroll
    for (int j = 0; j < 16; ++j)
        s += Xc[((size_t)b*1024 + d*16 + j)*128 + c];
    out[((size_t)b*128 + c)*64 + d] = s * (1.f/16.f);
}

extern "C" void kernel_launch(void* const* d_in, const int* in_sizes, int n_in,
                              void* d_out, int out_size, void* d_ws, size_t ws_size,
                              hipStream_t stream)
{
    (void)in_sizes; (void)n_in; (void)out_size; (void)ws_size;
    const float* x_in    = (const float*)d_in[0];
    const float* ln1_g   = (const float*)d_in[1];
    const float* ln1_b   = (const float*)d_in[2];
    const float* ln2_g   = (const float*)d_in[3];
    const float* ln2_b   = (const float*)d_in[4];
    const float* Lam_re  = (const float*)d_in[5];
    const float* Lam_im  = (const float*)d_in[6];
    const float* B_re    = (const float*)d_in[7];
    const float* B_im    = (const float*)d_in[8];
    const float* C_re    = (const float*)d_in[9];
    const float* C_im    = (const float*)d_in[10];
    const float* D_skip  = (const float*)d_in[11];
    const float* log_step= (const float*)d_in[12];
    const float* W1      = (const float*)d_in[13];
    const float* b1      = (const float*)d_in[14];
    const float* W2      = (const float*)d_in[15];
    const float* b2      = (const float*)d_in[16];
    const float* conv1_w = (const float*)d_in[17];
    const float* conv1_b = (const float*)d_in[18];
    const float* conv2_w = (const float*)d_in[19];
    const float* conv2_b = (const float*)d_in[20];
    float* out = (float*)d_out;

    // Workspace: X fp32 64MB @0 | C fp32 [BT,256] 128MB @64MB | Abf bf16 32MB @192MB
    //            | params+carry ~3.2MB @224MB  (total ~227MB)
    char* ws = (char*)d_ws;
    float* X   = (float*)(ws);
    float* C   = (float*)(ws + (size_t)67108864);
    bf16*  Abf = (bf16*) (ws + (size_t)201326592);
    char*  wreg = ws + (size_t)234881024;
    bf16*   Wbu_t = (bf16*)(wreg);                  // 131072 B
    bf16*   Wc_t  = (bf16*)(wreg + 131072);         // 131072 B
    bf16*   W1t   = (bf16*)(wreg + 262144);         // 131072 B
    bf16*   W2t   = (bf16*)(wreg + 393216);         // 131072 B
    float4* coefs = (float4*)(wreg + 524288);       // 4096 B
    float*  wT1   = (float*)(wreg + 528384);        // 327680 B
    float*  wT2   = (float*)(wreg + 856064);        // 327680 B
    float2* carry = (float2*)(wreg + 1183744);      // 2 MB

    prep_s5<<<2, 128, 0, stream>>>(Lam_re, Lam_im, B_re, B_im, C_re, C_im, log_step,
                                   Wbu_t, Wc_t, coefs);
    prep_w12<<<512, 256, 0, stream>>>(W1, W2, W1t, W2t);
    prep_wT<<<640, 256, 0, stream>>>(conv1_w, conv2_w, wT1, wT2);

    for (int i = 0; i < 2; ++i) {
        const float* src = (i == 0) ? x_in : X;     // layer input / residual
        // ---- S5 sub-block ----
        ln_kernel<<<BT/4, 256, 0, stream>>>(src, Abf, ln1_g + i*HD, ln1_b + i*HD);
        gemm_mfma<128,256,0,bf16><<<dim3(BT/128, 2), 256, 0, stream>>>(
            Abf, Wbu_t + (size_t)i*256*128, C, nullptr, nullptr, nullptr, nullptr);
        scan_local<<<1024, 256, 0, stream>>>((float2*)C, coefs + i*NST, carry);
        scan_carry<<<16, 256, 0, stream>>>(carry, coefs + i*NST);
        scan_fix<<<1024, 256, 0, stream>>>((float2*)C, coefs + i*NST, carry);
        gemm_mfma<256,128,3,float><<<dim3(BT/128, 1), 256, 0, stream>>>(
            C, Wc_t + (size_t)i*128*256, X, nullptr, src, Abf, D_skip + i*HD);
        // ---- MLP sub-block ----
        ln_kernel<<<BT/4, 256, 0, stream>>>(X, Abf, ln2_g + i*HD, ln2_b + i*HD);
        gemm_mfma<128,256,1,bf16><<<dim3(BT/128, 2), 256, 0, stream>>>(
            Abf, W1t + (size_t)i*256*128, C, b1 + i*2*HD, nullptr, nullptr, nullptr);
        gemm_mfma<256,128,2,float><<<dim3(BT/128, 1), 256, 0, stream>>>(
            C, W2t + (size_t)i*128*256, X, b2 + i*HD, X, nullptr, nullptr);
    }

    // ---- head: conv1 (X->C) -> conv2 (C->X) -> pool (X->out) ----
    conv_kernel<<<dim3(32, 128), 128, 0, stream>>>(X, wT1, conv1_b, C, 4096, 2048);
    conv_kernel<<<dim3(32, 64),  128, 0, stream>>>(C, wT2, conv2_b, X, 2048, 1024);
    pool_kernel<<<1024, 256, 0, stream>>>(X, out);
}

// Round 4
// 1002.367 us; speedup vs baseline: 1.7808x; 1.1931x over previous
//
#include <hip/hip_runtime.h>
#include <math.h>

#define BATCH 32
#define TSEQ  4096
#define HD    128
#define NST   128
#define BT    (BATCH*TSEQ)     // 131072
#define LC    64               // scan chunk length
#define NCHK  (TSEQ/LC)        // 64 chunks

typedef unsigned short bf16;
typedef __attribute__((ext_vector_type(8))) short bf16x8;   // 8 bf16 = 4 VGPRs (MFMA A/B frag)
typedef __attribute__((ext_vector_type(4))) float f32x4;    // MFMA C/D frag

__device__ inline float bf2f(bf16 s) {
    union { unsigned int u; float f; } v; v.u = ((unsigned int)s) << 16; return v.f;
}
__device__ inline bf16 f2bf(float f) {
    union { float f; unsigned int u; } v; v.f = f;
    unsigned int u = v.u;
    unsigned int r = (u + 0x7fffu + ((u >> 16) & 1u)) >> 16;
    return (bf16)r;
}
__device__ inline float2 cmul2(float2 a, float2 b) {
    return make_float2(a.x*b.x - a.y*b.y, a.x*b.y + a.y*b.x);
}
__device__ inline float gelu_f(float x) {
    return 0.5f * x * (1.f + erff(x * 0.70710678118654752f));
}

// ---------------- S5 parameter prep (bf16, transposed [N][K] for MFMA B) ----------------
__global__ void prep_s5(const float* __restrict__ Lam_re, const float* __restrict__ Lam_im,
                        const float* __restrict__ B_re,  const float* __restrict__ B_im,
                        const float* __restrict__ C_re,  const float* __restrict__ C_im,
                        const float* __restrict__ log_step,
                        bf16* __restrict__ Wbu_t,   // [2][256][128]  row 2n=Re, 2n+1=Im
                        bf16* __restrict__ Wc_t,    // [2][128][256]  col 2n=2Cre, 2n+1=-2Cim
                        float4* __restrict__ coefs)
{
    int i = blockIdx.x;          // layer
    int n = threadIdx.x;         // state
    int in = i*NST + n;
    float lr = Lam_re[in], li = Lam_im[in];
    float dt = expf(log_step[in]);
    float ldr = lr*dt, ldi = li*dt;
    float ea = expf(ldr);
    float ar = ea*cosf(ldi), ai = ea*sinf(ldi);
    float xx = ar - 1.f, yy = ai;
    float den = lr*lr + li*li;
    float sr = (xx*lr + yy*li)/den;
    float si = (yy*lr - xx*li)/den;
    float2 p = make_float2(ar, ai);
    #pragma unroll
    for (int q = 0; q < 6; ++q) p = cmul2(p, p);   // a^64
    coefs[in] = make_float4(ar, ai, p.x, p.y);

    const float* br = B_re + (size_t)in*HD;
    const float* bi = B_im + (size_t)in*HD;
    bf16* wb = Wbu_t + (size_t)i*256*128;
    for (int h = 0; h < HD; ++h) {
        float brv = br[h], biv = bi[h];
        wb[(2*n)*128 + h]   = f2bf(sr*brv - si*biv);
        wb[(2*n+1)*128 + h] = f2bf(sr*biv + si*brv);
    }
    const float* cr = C_re + (size_t)i*HD*NST;
    const float* ci = C_im + (size_t)i*HD*NST;
    bf16* wc = Wc_t + (size_t)i*128*256;
    for (int h = 0; h < HD; ++h) {
        wc[h*256 + 2*n]   = f2bf( 2.f * cr[h*NST + n]);
        wc[h*256 + 2*n+1] = f2bf(-2.f * ci[h*NST + n]);
    }
}

// MLP weights -> bf16 transposed [N][K]
__global__ void prep_w12(const float* __restrict__ W1, const float* __restrict__ W2,
                         bf16* __restrict__ W1t, bf16* __restrict__ W2t)
{
    int idx = blockIdx.x*256 + threadIdx.x;
    if (idx < 65536) {                       // W1t[i][f][h] = W1[i][h][f]
        int i = idx >> 15, r = idx & 32767;
        int f = r >> 7, h = r & 127;
        W1t[idx] = f2bf(W1[(size_t)i*32768 + h*256 + f]);
    } else if (idx < 131072) {               // W2t[i][h][f] = W2[i][f][h]
        int t = idx - 65536;
        int i = t >> 15, r = t & 32767;
        int h = r >> 8, f = r & 255;
        W2t[t] = f2bf(W2[(size_t)i*32768 + f*128 + h]);
    }
}

// conv weights [c][ic][tap] -> bf16 [c][tap*128+ic]  (im2col B-matrix, K=640)
__global__ void prep_wB(const float* __restrict__ w1, const float* __restrict__ w2,
                        bf16* __restrict__ wB1, bf16* __restrict__ wB2)
{
    int idx = blockIdx.x*256 + threadIdx.x;
    if (idx >= 163840) return;
    const float* w = (idx < 81920) ? w1 : w2;
    bf16* wb       = (idx < 81920) ? wB1 : wB2;
    int r   = idx % 81920;
    int c   = r / 640;
    int tap = (r % 640) / 128;
    int ic  = r % 128;
    wb[r] = f2bf(w[(c*128 + ic)*5 + tap]);
}

// ---------------- LayerNorm (H=128): one wave per row, bf16 out ----------------
__global__ __launch_bounds__(256) void ln_kernel(const float* __restrict__ X,
                                                 bf16* __restrict__ out,
                                                 const float* __restrict__ g,
                                                 const float* __restrict__ b)
{
    int lane = threadIdx.x & 63;
    size_t row = (size_t)blockIdx.x*4 + (threadIdx.x >> 6);
    const float* xr = X + row*HD;
    float2 v = *(const float2*)&xr[lane*2];
    float s = v.x + v.y;
    float s2 = v.x*v.x + v.y*v.y;
    #pragma unroll
    for (int off = 32; off >= 1; off >>= 1) {
        s  += __shfl_xor(s,  off);
        s2 += __shfl_xor(s2, off);
    }
    float mu  = s * (1.f/128.f);
    float var = s2 * (1.f/128.f) - mu*mu;
    float rs  = rsqrtf(var + 1e-5f);
    float2 gv = *(const float2*)&g[lane*2];
    float2 bv = *(const float2*)&b[lane*2];
    float ox = (v.x-mu)*rs*gv.x + bv.x;
    float oy = (v.y-mu)*rs*gv.y + bv.y;
    *(ushort2*)&out[row*HD + lane*2] = make_ushort2(f2bf(ox), f2bf(oy));
}

// ---------------- bf16 MFMA GEMM, 128x128 tile, BK=64, fused epilogues ----------------
// EPI: 0 none; 1 gelu(acc+bias); 2 acc+bias+resid; 3 resid+acc+u*dskip
template<int K, int NCOL, int EPI, typename TA>
__global__ __launch_bounds__(256) void gemm_mfma(
    const TA*  __restrict__ A,
    const bf16* __restrict__ Bt,
    float* out,                      // may alias resid (same-elem read-then-write only)
    const float* __restrict__ bias,
    const float* resid,
    const bf16* __restrict__ u,
    const float* __restrict__ dskip)
{
    __shared__ bf16 As[128][72];     // +8 pad: row stride 144B kills frag-read conflicts
    __shared__ bf16 Bs[128][72];
    int tid  = threadIdx.x;
    int lane = tid & 63;
    int wave = tid >> 6;
    int wm = wave >> 1, wn = wave & 1;          // 2x2 waves, 64x64 each
    int quad = lane >> 4, cl = lane & 15;
    int row0 = blockIdx.x * 128;
    int col0 = blockIdx.y * 128;

    f32x4 acc[4][4] = {};

    for (int k0 = 0; k0 < K; k0 += 64) {
        if constexpr (sizeof(TA) == 2) {
            #pragma unroll
            for (int it = 0; it < 4; ++it) {
                int idx = it*256 + tid;              // 0..1023
                int r = idx >> 3, kof = (idx & 7) * 8;
                bf16x8 v = *(const bf16x8*)(A + (size_t)(row0 + r)*K + k0 + kof);
                *(bf16x8*)&As[r][kof] = v;
            }
        } else {
            #pragma unroll
            for (int it = 0; it < 8; ++it) {
                int idx = it*256 + tid;              // 0..2047
                int r = idx >> 4, kof = (idx & 15) * 4;
                float4 f = *(const float4*)(A + (size_t)(row0 + r)*K + k0 + kof);
                ushort4 h;
                h.x = f2bf(f.x); h.y = f2bf(f.y); h.z = f2bf(f.z); h.w = f2bf(f.w);
                *(ushort4*)&As[r][kof] = h;
            }
        }
        #pragma unroll
        for (int it = 0; it < 4; ++it) {
            int idx = it*256 + tid;
            int n = idx >> 3, kof = (idx & 7) * 8;
            bf16x8 v = *(const bf16x8*)(Bt + (size_t)(col0 + n)*K + k0 + kof);
            *(bf16x8*)&Bs[n][kof] = v;
        }
        __syncthreads();
        #pragma unroll
        for (int kk = 0; kk < 64; kk += 32) {
            bf16x8 af[4], bfr[4];
            #pragma unroll
            for (int i = 0; i < 4; ++i)
                af[i] = *(const bf16x8*)&As[wm*64 + i*16 + cl][kk + quad*8];
            #pragma unroll
            for (int j = 0; j < 4; ++j)
                bfr[j] = *(const bf16x8*)&Bs[wn*64 + j*16 + cl][kk + quad*8];
            #pragma unroll
            for (int i = 0; i < 4; ++i)
                #pragma unroll
                for (int j = 0; j < 4; ++j)
                    acc[i][j] = __builtin_amdgcn_mfma_f32_16x16x32_bf16(
                                    af[i], bfr[j], acc[i][j], 0, 0, 0);
        }
        __syncthreads();
    }

    // ---- epilogue: C/D layout col=lane&15, row=quad*4+reg ----
    #pragma unroll
    for (int j = 0; j < 4; ++j) {
        int gcol = col0 + wn*64 + j*16 + cl;
        float bias_v = (EPI == 1 || EPI == 2) ? bias[gcol] : 0.f;
        float dv     = (EPI == 3) ? dskip[gcol] : 0.f;
        #pragma unroll
        for (int i = 0; i < 4; ++i) {
            #pragma unroll
            for (int r = 0; r < 4; ++r) {
                int grow = row0 + wm*64 + i*16 + quad*4 + r;
                size_t oidx = (size_t)grow*NCOL + gcol;
                float v = acc[i][j][r];
                if (EPI == 1)      v = gelu_f(v + bias_v);
                else if (EPI == 2) v = v + bias_v + resid[oidx];
                else if (EPI == 3) v = resid[oidx] + v + bf2f(u[oidx])*dv;
                out[oidx] = v;
            }
        }
    }
}

// ---------------- conv1d stride2 k=5 pad2 as implicit-im2col MFMA GEMM ----------------
// out[b*Lout+l][c] = relu(bias[c] + sum_{tap,ic} X[b][2l-2+tap][ic] * wB[c][tap*128+ic])
// A-row for output l = 640 floats at X[b] + (2l-2)*128 (taps contiguous); edges zero-padded.
__global__ __launch_bounds__(256) void conv_mfma(
    const float* __restrict__ X,
    const bf16* __restrict__ wB,    // [128][640]
    const float* __restrict__ bias,
    float* __restrict__ out,        // [B*Lout][128]
    int Tin, int Lout)
{
    __shared__ bf16 As[128][72];
    __shared__ bf16 Bs[128][72];
    int tid  = threadIdx.x;
    int lane = tid & 63;
    int wave = tid >> 6;
    int wm = wave >> 1, wn = wave & 1;
    int quad = lane >> 4, cl = lane & 15;
    int row0 = blockIdx.x * 128;               // global output row (Lout % 128 == 0)
    int b  = row0 / Lout;
    int l0 = row0 % Lout;
    const float* Xb = X + (size_t)b*Tin*128;

    f32x4 acc[4][4] = {};

    for (int k0 = 0; k0 < 640; k0 += 64) {
        int tap = k0 / 128;                    // 64-chunk never crosses a tap
        int icb = k0 % 128;
        // stage A: 128 rows x 64 k, t = 2*(l0+r)-2+tap, zero outside [0,Tin)
        #pragma unroll
        for (int it = 0; it < 8; ++it) {
            int idx = it*256 + tid;
            int r = idx >> 4, kof = (idx & 15) * 4;
            int t = 2*(l0 + r) - 2 + tap;
            ushort4 h = make_ushort4(0,0,0,0);
            if (t >= 0 && t < Tin) {
                float4 f = *(const float4*)(Xb + (size_t)t*128 + icb + kof);
                h.x = f2bf(f.x); h.y = f2bf(f.y); h.z = f2bf(f.z); h.w = f2bf(f.w);
            }
            *(ushort4*)&As[r][kof] = h;
        }
        // stage B: 128 cols x 64 k
        #pragma unroll
        for (int it = 0; it < 4; ++it) {
            int idx = it*256 + tid;
            int n = idx >> 3, kof = (idx & 7) * 8;
            *(bf16x8*)&Bs[n][kof] = *(const bf16x8*)(wB + (size_t)n*640 + k0 + kof);
        }
        __syncthreads();
        #pragma unroll
        for (int kk = 0; kk < 64; kk += 32) {
            bf16x8 af[4], bfr[4];
            #pragma unroll
            for (int i = 0; i < 4; ++i)
                af[i] = *(const bf16x8*)&As[wm*64 + i*16 + cl][kk + quad*8];
            #pragma unroll
            for (int j = 0; j < 4; ++j)
                bfr[j] = *(const bf16x8*)&Bs[wn*64 + j*16 + cl][kk + quad*8];
            #pragma unroll
            for (int i = 0; i < 4; ++i)
                #pragma unroll
                for (int j = 0; j < 4; ++j)
                    acc[i][j] = __builtin_amdgcn_mfma_f32_16x16x32_bf16(
                                    af[i], bfr[j], acc[i][j], 0, 0, 0);
        }
        __syncthreads();
    }

    #pragma unroll
    for (int j = 0; j < 4; ++j) {
        int gcol = wn*64 + j*16 + cl;
        float bv = bias[gcol];
        #pragma unroll
        for (int i = 0; i < 4; ++i) {
            #pragma unroll
            for (int r = 0; r < 4; ++r) {
                int grow = row0 + wm*64 + i*16 + quad*4 + r;
                float v = acc[i][j][r] + bv;
                out[(size_t)grow*128 + gcol] = v > 0.f ? v : 0.f;
            }
        }
    }
}

// ---------------- chunked scan: x_t = a*x_{t-1} + Bu_t (fp32) ----------------
__global__ __launch_bounds__(256) void scan_local(float2* __restrict__ xs,
                                                  const float4* __restrict__ coefs,
                                                  float2* __restrict__ carry)
{
    int flat = blockIdx.x*256 + threadIdx.x;  // 2^18
    int n = flat & 127;
    int b = (flat >> 7) & 31;
    int c = flat >> 12;
    float4 cf = coefs[n];
    float2 a = make_float2(cf.x, cf.y);
    float2* base = xs + ((size_t)(b*TSEQ + c*LC))*NST + n;
    float2 x = make_float2(0.f, 0.f);
    for (int j = 0; j < LC; ++j) {
        float2 v = base[(size_t)j*NST];
        x = make_float2(a.x*x.x - a.y*x.y + v.x, a.x*x.y + a.y*x.x + v.y);
        base[(size_t)j*NST] = x;
    }
    carry[c*(BATCH*NST) + b*NST + n] = x;
}

__global__ void scan_carry(float2* __restrict__ carry, const float4* __restrict__ coefs)
{
    int flat = blockIdx.x*256 + threadIdx.x;  // 4096 = B*N
    int n = flat & 127;
    float4 cf = coefs[n];
    float2 aL = make_float2(cf.z, cf.w);
    float2 x = make_float2(0.f, 0.f);
    for (int c = 0; c < NCHK; ++c) {
        float2* p = carry + c*(BATCH*NST) + flat;
        float2 v = *p;
        *p = x;                                // exclusive prefix
        x = make_float2(aL.x*x.x - aL.y*x.y + v.x, aL.x*x.y + aL.y*x.x + v.y);
    }
}

__global__ __launch_bounds__(256) void scan_fix(float2* __restrict__ xs,
                                                const float4* __restrict__ coefs,
                                                const float2* __restrict__ carry)
{
    int flat = blockIdx.x*256 + threadIdx.x;
    int n = flat & 127;
    int b = (flat >> 7) & 31;
    int c = flat >> 12;
    if (c == 0) return;
    float2 cin = carry[c*(BATCH*NST) + b*NST + n];
    float4 cf = coefs[n];
    float2 a = make_float2(cf.x, cf.y);
    float2* base = xs + ((size_t)(b*TSEQ + c*LC))*NST + n;
    float2 p = a;
    for (int j = 0; j < LC; ++j) {
        float2 add = cmul2(p, cin);
        float2 v = base[(size_t)j*NST];
        base[(size_t)j*NST] = make_float2(v.x + add.x, v.y + add.y);
        p = cmul2(p, a);
    }
}

// ---------------- adaptive avg pool: [32][1024][128] -> [32][128][64] ----------------
__global__ void pool_kernel(const float* __restrict__ Xc, float* __restrict__ out)
{
    int idx = blockIdx.x*256 + threadIdx.x;   // 262144
    int c = idx & 127;
    int d = (idx >> 7) & 63;
    int b = idx >> 13;
    float s = 0.f;
    #pragma unroll
    for (int j = 0; j < 16; ++j)
        s += Xc[((size_t)b*1024 + d*16 + j)*128 + c];
    out[((size_t)b*128 + c)*64 + d] = s * (1.f/16.f);
}

extern "C" void kernel_launch(void* const* d_in, const int* in_sizes, int n_in,
                              void* d_out, int out_size, void* d_ws, size_t ws_size,
                              hipStream_t stream)
{
    (void)in_sizes; (void)n_in; (void)out_size; (void)ws_size;
    const float* x_in    = (const float*)d_in[0];
    const float* ln1_g   = (const float*)d_in[1];
    const float* ln1_b   = (const float*)d_in[2];
    const float* ln2_g   = (const float*)d_in[3];
    const float* ln2_b   = (const float*)d_in[4];
    const float* Lam_re  = (const float*)d_in[5];
    const float* Lam_im  = (const float*)d_in[6];
    const float* B_re    = (const float*)d_in[7];
    const float* B_im    = (const float*)d_in[8];
    const float* C_re    = (const float*)d_in[9];
    const float* C_im    = (const float*)d_in[10];
    const float* D_skip  = (const float*)d_in[11];
    const float* log_step= (const float*)d_in[12];
    const float* W1      = (const float*)d_in[13];
    const float* b1      = (const float*)d_in[14];
    const float* W2      = (const float*)d_in[15];
    const float* b2      = (const float*)d_in[16];
    const float* conv1_w = (const float*)d_in[17];
    const float* conv1_b = (const float*)d_in[18];
    const float* conv2_w = (const float*)d_in[19];
    const float* conv2_b = (const float*)d_in[20];
    float* out = (float*)d_out;

    // Workspace: X fp32 64MB @0 | C fp32 [BT,256] 128MB @64MB | Abf bf16 32MB @192MB
    //            | params+carry ~2.95MB @224MB
    char* ws = (char*)d_ws;
    float* X   = (float*)(ws);
    float* C   = (float*)(ws + (size_t)67108864);
    bf16*  Abf = (bf16*) (ws + (size_t)201326592);
    char*  wreg = ws + (size_t)234881024;
    bf16*   Wbu_t = (bf16*)(wreg);                  // 131072 B
    bf16*   Wc_t  = (bf16*)(wreg + 131072);         // 131072 B
    bf16*   W1t   = (bf16*)(wreg + 262144);         // 131072 B
    bf16*   W2t   = (bf16*)(wreg + 393216);         // 131072 B
    float4* coefs = (float4*)(wreg + 524288);       // 4096 B
    bf16*   wB1   = (bf16*)(wreg + 528384);         // 163840 B
    bf16*   wB2   = (bf16*)(wreg + 692224);         // 163840 B
    float2* carry = (float2*)(wreg + 856064);       // 2 MB

    prep_s5<<<2, 128, 0, stream>>>(Lam_re, Lam_im, B_re, B_im, C_re, C_im, log_step,
                                   Wbu_t, Wc_t, coefs);
    prep_w12<<<512, 256, 0, stream>>>(W1, W2, W1t, W2t);
    prep_wB<<<640, 256, 0, stream>>>(conv1_w, conv2_w, wB1, wB2);

    for (int i = 0; i < 2; ++i) {
        const float* src = (i == 0) ? x_in : X;     // layer input / residual
        // ---- S5 sub-block ----
        ln_kernel<<<BT/4, 256, 0, stream>>>(src, Abf, ln1_g + i*HD, ln1_b + i*HD);
        gemm_mfma<128,256,0,bf16><<<dim3(BT/128, 2), 256, 0, stream>>>(
            Abf, Wbu_t + (size_t)i*256*128, C, nullptr, nullptr, nullptr, nullptr);
        scan_local<<<1024, 256, 0, stream>>>((float2*)C, coefs + i*NST, carry);
        scan_carry<<<16, 256, 0, stream>>>(carry, coefs + i*NST);
        scan_fix<<<1024, 256, 0, stream>>>((float2*)C, coefs + i*NST, carry);
        gemm_mfma<256,128,3,float><<<dim3(BT/128, 1), 256, 0, stream>>>(
            C, Wc_t + (size_t)i*128*256, X, nullptr, src, Abf, D_skip + i*HD);
        // ---- MLP sub-block ----
        ln_kernel<<<BT/4, 256, 0, stream>>>(X, Abf, ln2_g + i*HD, ln2_b + i*HD);
        gemm_mfma<128,256,1,bf16><<<dim3(BT/128, 2), 256, 0, stream>>>(
            Abf, W1t + (size_t)i*256*128, C, b1 + i*2*HD, nullptr, nullptr, nullptr);
        gemm_mfma<256,128,2,float><<<dim3(BT/128, 1), 256, 0, stream>>>(
            C, W2t + (size_t)i*128*256, X, b2 + i*HD, X, nullptr, nullptr);
    }

    // ---- head: conv1 (X->C) -> conv2 (C->X) -> pool (X->out) ----
    conv_mfma<<<512, 256, 0, stream>>>(X, wB1, conv1_b, C, 4096, 2048);
    conv_mfma<<<256, 256, 0, stream>>>(C, wB2, conv2_b, X, 2048, 1024);
    pool_kernel<<<1024, 256, 0, stream>>>(X, out);
}